// Round 7
// baseline (14591.481 us; speedup 1.0000x reference)
//
#include <hip/hip_runtime.h>
#include <cmath>

// Problem dims (fixed at compile time)
constexpr int Bv  = 64;
constexpr int T   = 512;
constexpr int H   = 512;   // h_third
constexpr int OUTD = 256;
constexpr int M   = Bv * T;  // 32768 rows for the big GEMMs

// ---------------------------------------------------------------------------
// GEMM: C[M,N] = act(A[M,512] @ W[512,N] + b1[N] (+ b2[N]))   (fp32, K=512)
// 64x64 tile, 256 threads, 4x4 microtile per thread.
// ---------------------------------------------------------------------------
__global__ __launch_bounds__(256) void gemm_bias_act(
    const float* __restrict__ A, const float* __restrict__ W,
    const float* __restrict__ b1, const float* __restrict__ b2,
    float* __restrict__ C, int N, int do_tanh)
{
    constexpr int K = 512;
    __shared__ float As[16][64];   // [k][m] (transposed on store)
    __shared__ float Bs[16][64];   // [k][n]

    const int tid  = threadIdx.x;
    const int row0 = blockIdx.x * 64;
    const int col0 = blockIdx.y * 64;
    const int tx = tid & 15, ty = tid >> 4;
    const int la_m = tid >> 2, la_k = (tid & 3) * 4;
    const int lb_k = tid >> 4, lb_n = (tid & 15) * 4;

    float acc[4][4] = {};

    const float* Aptr = A + (size_t)(row0 + la_m) * K + la_k;
    const float* Wptr = W + (size_t)lb_k * N + col0 + lb_n;

    for (int k0 = 0; k0 < K; k0 += 16) {
        const float4 a4 = *(const float4*)(Aptr + k0);
        const float4 b4 = *(const float4*)(Wptr + (size_t)k0 * N);
        As[la_k + 0][la_m] = a4.x;
        As[la_k + 1][la_m] = a4.y;
        As[la_k + 2][la_m] = a4.z;
        As[la_k + 3][la_m] = a4.w;
        *(float4*)&Bs[lb_k][lb_n] = b4;
        __syncthreads();
        #pragma unroll
        for (int k = 0; k < 16; ++k) {
            const float4 av = *(const float4*)&As[k][ty * 4];
            const float4 bv = *(const float4*)&Bs[k][tx * 4];
            acc[0][0] = fmaf(av.x, bv.x, acc[0][0]);
            acc[0][1] = fmaf(av.x, bv.y, acc[0][1]);
            acc[0][2] = fmaf(av.x, bv.z, acc[0][2]);
            acc[0][3] = fmaf(av.x, bv.w, acc[0][3]);
            acc[1][0] = fmaf(av.y, bv.x, acc[1][0]);
            acc[1][1] = fmaf(av.y, bv.y, acc[1][1]);
            acc[1][2] = fmaf(av.y, bv.z, acc[1][2]);
            acc[1][3] = fmaf(av.y, bv.w, acc[1][3]);
            acc[2][0] = fmaf(av.z, bv.x, acc[2][0]);
            acc[2][1] = fmaf(av.z, bv.y, acc[2][1]);
            acc[2][2] = fmaf(av.z, bv.z, acc[2][2]);
            acc[2][3] = fmaf(av.z, bv.w, acc[2][3]);
            acc[3][0] = fmaf(av.w, bv.x, acc[3][0]);
            acc[3][1] = fmaf(av.w, bv.y, acc[3][1]);
            acc[3][2] = fmaf(av.w, bv.z, acc[3][2]);
            acc[3][3] = fmaf(av.w, bv.w, acc[3][3]);
        }
        __syncthreads();
    }

    float4 bias = *(const float4*)&b1[col0 + tx * 4];
    if (b2 != nullptr) {
        const float4 e = *(const float4*)&b2[col0 + tx * 4];
        bias.x += e.x; bias.y += e.y; bias.z += e.z; bias.w += e.w;
    }
    #pragma unroll
    for (int i = 0; i < 4; ++i) {
        float4 v;
        v.x = acc[i][0] + bias.x;
        v.y = acc[i][1] + bias.y;
        v.z = acc[i][2] + bias.z;
        v.w = acc[i][3] + bias.w;
        if (do_tanh) {
            v.x = tanhf(v.x); v.y = tanhf(v.y); v.z = tanhf(v.z); v.w = tanhf(v.w);
        }
        *(float4*)&C[(size_t)(row0 + ty * 4 + i) * N + col0 + tx * 4] = v;
    }
}

// ---------------------------------------------------------------------------
// hs linear scan, in place: buf holds tanh(x@Ws+bs) on entry, hs on exit.
// ---------------------------------------------------------------------------
__global__ __launch_bounds__(256) void scan_hs_kernel(
    float* __restrict__ buf, const float* __restrict__ tau)
{
    const int h  = blockIdx.x * 256 + threadIdx.x;
    const int b0 = blockIdx.y * 4;
    const float inv = 1.0f / tau[h];
    const float am  = 1.0f - inv;
    float s0 = 0.f, s1 = 0.f, s2 = 0.f, s3 = 0.f;
    const size_t bs_ = (size_t)T * H;
    const size_t i0 = (size_t)b0 * bs_ + h;
    for (int t = 0; t < T; ++t) {
        const size_t o = i0 + (size_t)t * H;
        const float x0 = buf[o];
        const float x1 = buf[o + bs_];
        const float x2 = buf[o + 2 * bs_];
        const float x3 = buf[o + 3 * bs_];
        s0 = am * s0 + inv * x0;
        s1 = am * s1 + inv * x1;
        s2 = am * s2 + inv * x2;
        s3 = am * s3 + inv * x3;
        buf[o]           = s0;
        buf[o + bs_]     = s1;
        buf[o + 2 * bs_] = s2;
        buf[o + 3 * bs_] = s3;
    }
}

// ---------------------------------------------------------------------------
// zero the cross-block progress flags (d_out scratch region)
// ---------------------------------------------------------------------------
__global__ void zero_flags_kernel(int* __restrict__ prog)
{
    prog[threadIdx.x] = 0;
}

// ---------------------------------------------------------------------------
// Nonlinear recurrence, weight-in-registers, 4 blocks per batch row.
//   h_t = (1-inv)*h_{t-1} + inv * tanh( U[b,t,:] + h_{t-1} @ Wr )
// Grid = 256 blocks (1 per CU, all co-resident). Block (r,p): batch row r,
// cols [128p,128p+128). 512 threads: cg = tid&31 -> 4 cols, s = tid>>5 ->
// k-slice [32s,32s+32). Each thread holds its 32x4 weight slab in 128 VGPRs,
// as 32 NAMED float4s (SROA-proof) + amdgpu_waves_per_eu(2,2) so the backend
// does not spill them chasing occupancy (round-3 failure: VGPR=88, w[] in
// scratch, +34 GB FETCH).
// Cross-block state exchange per step via agent-scope release/acquire flags.
// ---------------------------------------------------------------------------
#define WLOAD(i) const float4 w##i = *(const float4*)&Wr[(size_t)(k0 + (i)) * H + j0];

#define FMAG(wa, wb, wc, wd)                              \
    acc.x = fmaf(h4.x, wa.x, acc.x);                      \
    acc.y = fmaf(h4.x, wa.y, acc.y);                      \
    acc.z = fmaf(h4.x, wa.z, acc.z);                      \
    acc.w = fmaf(h4.x, wa.w, acc.w);                      \
    acc.x = fmaf(h4.y, wb.x, acc.x);                      \
    acc.y = fmaf(h4.y, wb.y, acc.y);                      \
    acc.z = fmaf(h4.y, wb.z, acc.z);                      \
    acc.w = fmaf(h4.y, wb.w, acc.w);                      \
    acc.x = fmaf(h4.z, wc.x, acc.x);                      \
    acc.y = fmaf(h4.z, wc.y, acc.y);                      \
    acc.z = fmaf(h4.z, wc.z, acc.z);                      \
    acc.w = fmaf(h4.z, wc.w, acc.w);                      \
    acc.x = fmaf(h4.w, wd.x, acc.x);                      \
    acc.y = fmaf(h4.w, wd.y, acc.y);                      \
    acc.z = fmaf(h4.w, wd.z, acc.z);                      \
    acc.w = fmaf(h4.w, wd.w, acc.w);

__global__ __launch_bounds__(512)
__attribute__((amdgpu_waves_per_eu(2, 2)))
void recur_kernel(
    const float* __restrict__ U, float* __restrict__ Hout,
    const float* __restrict__ Wr, const float* __restrict__ tau,
    int* __restrict__ prog)
{
    __shared__ float h_lds[H];          // full previous state h_{t-1}
    __shared__ float accb[16][128];     // partials: [k-slice][local col]

    const int tid = threadIdx.x;
    const int bid = blockIdx.x;
    // Swizzle so the 4 blocks of a row land on the same XCD (bid%8 = XCD):
    const int x = bid & 7, q = bid >> 3;
    const int r = (q >> 2) * 8 + x;     // batch row 0..63
    const int p = q & 3;                // column quarter 0..3
    const int p128 = p * 128;

    const int cg = tid & 31;            // col group: cols 4cg..4cg+3 (local)
    const int s  = tid >> 5;            // k-slice: [32s, 32s+32)
    const int k0 = s * 32;
    const int j0 = p128 + cg * 4;       // global col of this thread's 4 cols

    // ---- load this thread's 32x4 weight slab into NAMED registers ----
    WLOAD(0)  WLOAD(1)  WLOAD(2)  WLOAD(3)
    WLOAD(4)  WLOAD(5)  WLOAD(6)  WLOAD(7)
    WLOAD(8)  WLOAD(9)  WLOAD(10) WLOAD(11)
    WLOAD(12) WLOAD(13) WLOAD(14) WLOAD(15)
    WLOAD(16) WLOAD(17) WLOAD(18) WLOAD(19)
    WLOAD(20) WLOAD(21) WLOAD(22) WLOAD(23)
    WLOAD(24) WLOAD(25) WLOAD(26) WLOAD(27)
    WLOAD(28) WLOAD(29) WLOAD(30) WLOAD(31)

    // ---- per-owner state (threads 0..127 own column p128+tid) ----
    float inv = 0.f, am = 0.f, h_reg = 0.f;
    const float* Urow = nullptr;
    float*       Hrow = nullptr;
    if (tid < 128) {
        inv = 1.0f / tau[p128 + tid];
        am  = 1.0f - inv;
        Urow = U    + (size_t)r * T * H + p128 + tid;
        Hrow = Hout + (size_t)r * T * H + p128 + tid;
    }
    const float* Hall = Hout + (size_t)r * T * H;   // full row, for gather
    const int fbase = r * 4;

    h_lds[tid] = 0.0f;
    __syncthreads();

    for (int t = 0; t < T; ++t) {
        const float uval = (tid < 128) ? Urow[(size_t)t * H] : 0.0f;

        // ---- phase 1: partial matvec from registers ----
        float4 acc = make_float4(0.f, 0.f, 0.f, 0.f);
        float4 h4;
        h4 = *(const float4*)&h_lds[k0 +  0]; FMAG(w0,  w1,  w2,  w3)
        h4 = *(const float4*)&h_lds[k0 +  4]; FMAG(w4,  w5,  w6,  w7)
        h4 = *(const float4*)&h_lds[k0 +  8]; FMAG(w8,  w9,  w10, w11)
        h4 = *(const float4*)&h_lds[k0 + 12]; FMAG(w12, w13, w14, w15)
        h4 = *(const float4*)&h_lds[k0 + 16]; FMAG(w16, w17, w18, w19)
        h4 = *(const float4*)&h_lds[k0 + 20]; FMAG(w20, w21, w22, w23)
        h4 = *(const float4*)&h_lds[k0 + 24]; FMAG(w24, w25, w26, w27)
        h4 = *(const float4*)&h_lds[k0 + 28]; FMAG(w28, w29, w30, w31)
        *(float4*)&accb[s][cg * 4] = acc;
        __syncthreads();

        // ---- phase 2: reduce + state update (owners = threads 0..127) ----
        if (tid < 128) {
            float red = 0.f;
            #pragma unroll
            for (int ss = 0; ss < 16; ++ss) red += accb[ss][tid];
            const float a = red + uval;
            const float hnew = am * h_reg + inv * tanhf(a);
            h_reg = hnew;
            Hrow[(size_t)t * H] = hnew;       // publish shard
            h_lds[p128 + tid] = hnew;         // own part of h_t
            __threadfence();                  // make shard agent-visible
        }
        __syncthreads();                      // all owner fences done

        if (t + 1 < T) {
            // ---- post own flag, then spin for the 3 remote quarters ----
            if (tid == 0)
                __hip_atomic_store(&prog[fbase + p], t + 1,
                                   __ATOMIC_RELEASE, __HIP_MEMORY_SCOPE_AGENT);
            if (tid >= 1 && tid <= 3) {
                const int rq = (p + tid) & 3;
                while (__hip_atomic_load(&prog[fbase + rq],
                                         __ATOMIC_ACQUIRE, __HIP_MEMORY_SCOPE_AGENT) < t + 1) {}
            }
            __syncthreads();

            // ---- gather remote 384 state values into h_lds ----
            if (tid >= 128) {
                const int e = (p128 + tid) & 511;   // offsets past own shard
                h_lds[e] = Hall[(size_t)t * H + e];
            }
            __syncthreads();
        }
    }
}

// ---------------------------------------------------------------------------
extern "C" void kernel_launch(void* const* d_in, const int* in_sizes, int n_in,
                              void* d_out, int out_size, void* d_ws, size_t ws_size,
                              hipStream_t stream)
{
    const float* x     = (const float*)d_in[0];
    const float* Ws    = (const float*)d_in[1];
    const float* bs    = (const float*)d_in[2];
    const float* Wi    = (const float*)d_in[3];
    const float* bi    = (const float*)d_in[4];
    const float* Wc    = (const float*)d_in[5];
    const float* bc    = (const float*)d_in[6];
    const float* Wm    = (const float*)d_in[7];
    const float* bm    = (const float*)d_in[8];
    const float* Wir   = (const float*)d_in[9];
    const float* bir   = (const float*)d_in[10];
    const float* Wcr   = (const float*)d_in[11];
    const float* bcr   = (const float*)d_in[12];
    const float* tau_s = (const float*)d_in[13];
    const float* tau_i = (const float*)d_in[14];
    const float* tau_c = (const float*)d_in[15];
    float* out = (float*)d_out;

    float* bufA = (float*)d_ws;                 // [B,T,H]  64 MB
    float* bufB = bufA + (size_t)M * H;         // [B,T,H]  64 MB
    // progress flags live in d_out (pure scratch until final GEMM overwrites):
    // recur1 uses prog[0..255], recur2 uses prog[256..511].
    int* prog = (int*)d_out;

    const dim3 blk(256);

    zero_flags_kernel<<<1, 512, 0, stream>>>(prog);

    // 1) bufA = tanh(x @ Ws + bs)
    gemm_bias_act<<<dim3(M / 64, H / 64), blk, 0, stream>>>(x, Ws, bs, nullptr, bufA, H, 1);
    // 2) bufA = linear scan -> hs_all
    scan_hs_kernel<<<dim3(H / 256, Bv / 4), blk, 0, stream>>>(bufA, tau_s);
    // 3) bufB = hs_all @ Wi + (bi + bir)
    gemm_bias_act<<<dim3(M / 64, H / 64), blk, 0, stream>>>(bufA, Wi, bi, bir, bufB, H, 0);
    // 4) bufA = hi_all  (weight-in-register recurrence, 4 blocks/row)
    recur_kernel<<<dim3(256), dim3(512), 0, stream>>>(bufB, bufA, Wir, tau_i, prog);
    // 5) bufB = hi_all @ Wc + (bc + bcr)
    gemm_bias_act<<<dim3(M / 64, H / 64), blk, 0, stream>>>(bufA, Wc, bc, bcr, bufB, H, 0);
    // 6) bufA = hc_all
    recur_kernel<<<dim3(256), dim3(512), 0, stream>>>(bufB, bufA, Wcr, tau_c, prog + 256);
    // 7) out = hc_all @ Wm + bm
    gemm_bias_act<<<dim3(M / 64, OUTD / 64), blk, 0, stream>>>(bufA, Wm, bm, nullptr, out, OUTD, 0);
}

// Round 9
// 2624.296 us; speedup vs baseline: 5.5602x; 5.5602x over previous
//
#include <hip/hip_runtime.h>
#include <cmath>

// Problem dims (fixed at compile time)
constexpr int Bv  = 64;
constexpr int T   = 512;
constexpr int H   = 512;   // h_third
constexpr int OUTD = 256;
constexpr int M   = Bv * T;  // 32768 rows for the big GEMMs

// ---------------------------------------------------------------------------
// GEMM: C[M,N] = act(A[M,512] @ W[512,N] + b1[N] (+ b2[N]))   (fp32, K=512)
// 64x64 tile, 256 threads, 4x4 microtile per thread. (unchanged)
// ---------------------------------------------------------------------------
__global__ __launch_bounds__(256) void gemm_bias_act(
    const float* __restrict__ A, const float* __restrict__ W,
    const float* __restrict__ b1, const float* __restrict__ b2,
    float* __restrict__ C, int N, int do_tanh)
{
    constexpr int K = 512;
    __shared__ float As[16][64];   // [k][m] (transposed on store)
    __shared__ float Bs[16][64];   // [k][n]

    const int tid  = threadIdx.x;
    const int row0 = blockIdx.x * 64;
    const int col0 = blockIdx.y * 64;
    const int tx = tid & 15, ty = tid >> 4;
    const int la_m = tid >> 2, la_k = (tid & 3) * 4;
    const int lb_k = tid >> 4, lb_n = (tid & 15) * 4;

    float acc[4][4] = {};

    const float* Aptr = A + (size_t)(row0 + la_m) * K + la_k;
    const float* Wptr = W + (size_t)lb_k * N + col0 + lb_n;

    for (int k0 = 0; k0 < K; k0 += 16) {
        const float4 a4 = *(const float4*)(Aptr + k0);
        const float4 b4 = *(const float4*)(Wptr + (size_t)k0 * N);
        As[la_k + 0][la_m] = a4.x;
        As[la_k + 1][la_m] = a4.y;
        As[la_k + 2][la_m] = a4.z;
        As[la_k + 3][la_m] = a4.w;
        *(float4*)&Bs[lb_k][lb_n] = b4;
        __syncthreads();
        #pragma unroll
        for (int k = 0; k < 16; ++k) {
            const float4 av = *(const float4*)&As[k][ty * 4];
            const float4 bv = *(const float4*)&Bs[k][tx * 4];
            acc[0][0] = fmaf(av.x, bv.x, acc[0][0]);
            acc[0][1] = fmaf(av.x, bv.y, acc[0][1]);
            acc[0][2] = fmaf(av.x, bv.z, acc[0][2]);
            acc[0][3] = fmaf(av.x, bv.w, acc[0][3]);
            acc[1][0] = fmaf(av.y, bv.x, acc[1][0]);
            acc[1][1] = fmaf(av.y, bv.y, acc[1][1]);
            acc[1][2] = fmaf(av.y, bv.z, acc[1][2]);
            acc[1][3] = fmaf(av.y, bv.w, acc[1][3]);
            acc[2][0] = fmaf(av.z, bv.x, acc[2][0]);
            acc[2][1] = fmaf(av.z, bv.y, acc[2][1]);
            acc[2][2] = fmaf(av.z, bv.z, acc[2][2]);
            acc[2][3] = fmaf(av.z, bv.w, acc[2][3]);
            acc[3][0] = fmaf(av.w, bv.x, acc[3][0]);
            acc[3][1] = fmaf(av.w, bv.y, acc[3][1]);
            acc[3][2] = fmaf(av.w, bv.z, acc[3][2]);
            acc[3][3] = fmaf(av.w, bv.w, acc[3][3]);
        }
        __syncthreads();
    }

    float4 bias = *(const float4*)&b1[col0 + tx * 4];
    if (b2 != nullptr) {
        const float4 e = *(const float4*)&b2[col0 + tx * 4];
        bias.x += e.x; bias.y += e.y; bias.z += e.z; bias.w += e.w;
    }
    #pragma unroll
    for (int i = 0; i < 4; ++i) {
        float4 v;
        v.x = acc[i][0] + bias.x;
        v.y = acc[i][1] + bias.y;
        v.z = acc[i][2] + bias.z;
        v.w = acc[i][3] + bias.w;
        if (do_tanh) {
            v.x = tanhf(v.x); v.y = tanhf(v.y); v.z = tanhf(v.z); v.w = tanhf(v.w);
        }
        *(float4*)&C[(size_t)(row0 + ty * 4 + i) * N + col0 + tx * 4] = v;
    }
}

// ---------------------------------------------------------------------------
// hs linear scan, in place (unchanged)
// ---------------------------------------------------------------------------
__global__ __launch_bounds__(256) void scan_hs_kernel(
    float* __restrict__ buf, const float* __restrict__ tau)
{
    const int h  = blockIdx.x * 256 + threadIdx.x;
    const int b0 = blockIdx.y * 4;
    const float inv = 1.0f / tau[h];
    const float am  = 1.0f - inv;
    float s0 = 0.f, s1 = 0.f, s2 = 0.f, s3 = 0.f;
    const size_t bs_ = (size_t)T * H;
    const size_t i0 = (size_t)b0 * bs_ + h;
    for (int t = 0; t < T; ++t) {
        const size_t o = i0 + (size_t)t * H;
        const float x0 = buf[o];
        const float x1 = buf[o + bs_];
        const float x2 = buf[o + 2 * bs_];
        const float x3 = buf[o + 3 * bs_];
        s0 = am * s0 + inv * x0;
        s1 = am * s1 + inv * x1;
        s2 = am * s2 + inv * x2;
        s3 = am * s3 + inv * x3;
        buf[o]           = s0;
        buf[o + bs_]     = s1;
        buf[o + 2 * bs_] = s2;
        buf[o + 3 * bs_] = s3;
    }
}

// ---------------------------------------------------------------------------
// Nonlinear recurrence, weight-in-registers, 4 blocks per batch row.
//   h_t = (1-inv)*h_{t-1} + inv * tanh( U[b,t,:] + h_{t-1} @ Wr )
// Grid = 256 blocks (1/CU, all co-resident). Block (r,p): row r, cols
// [128p,128p+128). 512 thr: cg=tid&31 -> 4 cols, s=tid>>5 -> k-slice 32.
// Weights: 32 named float4 pinned via empty "+v" asm at loop top (defeats
// pressure-aware load sinking; round-7: VGPR=88, loads sunk into loop).
// Exchange: NO fences/acquire/release (they emit L2 wbl2/inv on gfx950 =
// round-7's ~11us/step). Owners publish (tag<<32|bits) via RELAXED agent
// atomics; readers poll the tagged word. Parity-2 buffer; skew<=1 step.
// Poison 0xAA -> negative tag -> never matches t+1 in [1,512].
// ---------------------------------------------------------------------------
#define WLOAD(i) float4 w##i = *(const float4*)&Wr[(size_t)(k0 + (i)) * H + j0];

#define PIN4(a,b,c,d) asm volatile("" :                                   \
    "+v"(a.x), "+v"(a.y), "+v"(a.z), "+v"(a.w),                           \
    "+v"(b.x), "+v"(b.y), "+v"(b.z), "+v"(b.w),                           \
    "+v"(c.x), "+v"(c.y), "+v"(c.z), "+v"(c.w),                           \
    "+v"(d.x), "+v"(d.y), "+v"(d.z), "+v"(d.w));

#define FMAG(wa, wb, wc, wd)                              \
    acc.x = fmaf(h4.x, wa.x, acc.x);                      \
    acc.y = fmaf(h4.x, wa.y, acc.y);                      \
    acc.z = fmaf(h4.x, wa.z, acc.z);                      \
    acc.w = fmaf(h4.x, wa.w, acc.w);                      \
    acc.x = fmaf(h4.y, wb.x, acc.x);                      \
    acc.y = fmaf(h4.y, wb.y, acc.y);                      \
    acc.z = fmaf(h4.y, wb.z, acc.z);                      \
    acc.w = fmaf(h4.y, wb.w, acc.w);                      \
    acc.x = fmaf(h4.z, wc.x, acc.x);                      \
    acc.y = fmaf(h4.z, wc.y, acc.y);                      \
    acc.z = fmaf(h4.z, wc.z, acc.z);                      \
    acc.w = fmaf(h4.z, wc.w, acc.w);                      \
    acc.x = fmaf(h4.w, wd.x, acc.x);                      \
    acc.y = fmaf(h4.w, wd.y, acc.y);                      \
    acc.z = fmaf(h4.w, wd.z, acc.z);                      \
    acc.w = fmaf(h4.w, wd.w, acc.w);

__global__ __launch_bounds__(512)
__attribute__((amdgpu_waves_per_eu(2, 2)))
void recur_kernel(
    const float* __restrict__ U, float* __restrict__ Hout,
    const float* __restrict__ Wr, const float* __restrict__ tau,
    unsigned long long* __restrict__ xbuf)
{
    __shared__ float h_lds[H];          // full previous state h_{t-1}
    __shared__ float accb[16][128];     // partials: [k-slice][local col]

    const int tid = threadIdx.x;
    const int bid = blockIdx.x;
    // Swizzle: 4 blocks of a row share bid&7 (same XCD under bid%8 mapping).
    const int x = bid & 7, q = bid >> 3;
    const int r = (q >> 2) * 8 + x;     // batch row 0..63
    const int p = q & 3;                // column quarter 0..3
    const int p128 = p * 128;

    const int cg = tid & 31;            // col group: cols 4cg..4cg+3 (local)
    const int s  = tid >> 5;            // k-slice: [32s, 32s+32)
    const int k0 = s * 32;
    const int j0 = p128 + cg * 4;       // global col of this thread's 4 cols

    // ---- load this thread's 32x4 weight slab into NAMED registers ----
    WLOAD(0)  WLOAD(1)  WLOAD(2)  WLOAD(3)
    WLOAD(4)  WLOAD(5)  WLOAD(6)  WLOAD(7)
    WLOAD(8)  WLOAD(9)  WLOAD(10) WLOAD(11)
    WLOAD(12) WLOAD(13) WLOAD(14) WLOAD(15)
    WLOAD(16) WLOAD(17) WLOAD(18) WLOAD(19)
    WLOAD(20) WLOAD(21) WLOAD(22) WLOAD(23)
    WLOAD(24) WLOAD(25) WLOAD(26) WLOAD(27)
    WLOAD(28) WLOAD(29) WLOAD(30) WLOAD(31)

    // ---- per-owner state (threads 0..127 own column p128+tid) ----
    float inv = 0.f, am = 0.f, h_reg = 0.f;
    const float* Urow = nullptr;
    float*       Hrow = nullptr;
    if (tid < 128) {
        inv = 1.0f / tau[p128 + tid];
        am  = 1.0f - inv;
        Urow = U    + (size_t)r * T * H + p128 + tid;
        Hrow = Hout + (size_t)r * T * H + p128 + tid;
    }
    unsigned long long* __restrict__ xrow = xbuf + (size_t)r * 2 * H;

    h_lds[tid] = 0.0f;
    __syncthreads();

    float uval = 0.f, unext = 0.f;
    if (tid < 128) uval = Urow[0];

    for (int t = 0; t < T; ++t) {
        // pin weight registers (loop-carried opaque def; no instructions)
        PIN4(w0,  w1,  w2,  w3)   PIN4(w4,  w5,  w6,  w7)
        PIN4(w8,  w9,  w10, w11)  PIN4(w12, w13, w14, w15)
        PIN4(w16, w17, w18, w19)  PIN4(w20, w21, w22, w23)
        PIN4(w24, w25, w26, w27)  PIN4(w28, w29, w30, w31)

        // prefetch next-step U (consumed next iteration's phase 2)
        if (tid < 128 && t + 1 < T) unext = Urow[(size_t)(t + 1) * H];

        // ---- phase 1: partial matvec from registers ----
        float4 acc = make_float4(0.f, 0.f, 0.f, 0.f);
        float4 h4;
        h4 = *(const float4*)&h_lds[k0 +  0]; FMAG(w0,  w1,  w2,  w3)
        h4 = *(const float4*)&h_lds[k0 +  4]; FMAG(w4,  w5,  w6,  w7)
        h4 = *(const float4*)&h_lds[k0 +  8]; FMAG(w8,  w9,  w10, w11)
        h4 = *(const float4*)&h_lds[k0 + 12]; FMAG(w12, w13, w14, w15)
        h4 = *(const float4*)&h_lds[k0 + 16]; FMAG(w16, w17, w18, w19)
        h4 = *(const float4*)&h_lds[k0 + 20]; FMAG(w20, w21, w22, w23)
        h4 = *(const float4*)&h_lds[k0 + 24]; FMAG(w24, w25, w26, w27)
        h4 = *(const float4*)&h_lds[k0 + 28]; FMAG(w28, w29, w30, w31)
        *(float4*)&accb[s][cg * 4] = acc;
        __syncthreads();

        // ---- phase 2: reduce + state update (owners = threads 0..127) ----
        if (tid < 128) {
            float red = 0.f;
            #pragma unroll
            for (int ss = 0; ss < 16; ++ss) red += accb[ss][tid];
            const float a = red + uval;
            const float hnew = am * h_reg + inv * tanhf(a);
            h_reg = hnew;
            if (t + 1 < T) {
                // publish (tag | bits) — relaxed, no cache maintenance
                const unsigned long long pv =
                    ((unsigned long long)(unsigned)(t + 1) << 32) |
                    (unsigned long long)__float_as_uint(hnew);
                __hip_atomic_store(&xrow[(size_t)(t & 1) * H + p128 + tid], pv,
                                   __ATOMIC_RELAXED, __HIP_MEMORY_SCOPE_AGENT);
            }
            Hrow[(size_t)t * H] = hnew;       // plain cached store (next kernel)
            h_lds[p128 + tid] = hnew;         // own part of h_t
        }

        // ---- gather remote 384 state values (poll tagged words) ----
        if (t + 1 < T) {
            if (tid >= 128) {
                const int e = (p128 + tid) & 511;   // remote cols
                unsigned long long* slot = &xrow[(size_t)(t & 1) * H + e];
                unsigned long long v;
                do {
                    v = __hip_atomic_load(slot, __ATOMIC_RELAXED,
                                          __HIP_MEMORY_SCOPE_AGENT);
                } while ((int)(v >> 32) != t + 1);
                h_lds[e] = __uint_as_float((unsigned)v);
            }
            uval = unext;
            __syncthreads();                  // h_t complete in LDS
        }
    }
}

// ---------------------------------------------------------------------------
extern "C" void kernel_launch(void* const* d_in, const int* in_sizes, int n_in,
                              void* d_out, int out_size, void* d_ws, size_t ws_size,
                              hipStream_t stream)
{
    const float* x     = (const float*)d_in[0];
    const float* Ws    = (const float*)d_in[1];
    const float* bs    = (const float*)d_in[2];
    const float* Wi    = (const float*)d_in[3];
    const float* bi    = (const float*)d_in[4];
    const float* Wc    = (const float*)d_in[5];
    const float* bc    = (const float*)d_in[6];
    const float* Wm    = (const float*)d_in[7];
    const float* bm    = (const float*)d_in[8];
    const float* Wir   = (const float*)d_in[9];
    const float* bir   = (const float*)d_in[10];
    const float* Wcr   = (const float*)d_in[11];
    const float* bcr   = (const float*)d_in[12];
    const float* tau_s = (const float*)d_in[13];
    const float* tau_i = (const float*)d_in[14];
    const float* tau_c = (const float*)d_in[15];
    float* out = (float*)d_out;

    float* bufA = (float*)d_ws;                 // [B,T,H]  64 MB
    float* bufB = bufA + (size_t)M * H;         // [B,T,H]  64 MB
    // Exchange buffers live at the start of d_out (poisoned 0xAA before every
    // launch -> negative tags; overwritten by the final GEMM afterwards).
    // Each: 64 rows x 2 parities x 512 cols x 8B = 512 KB.
    unsigned long long* xbuf1 = (unsigned long long*)d_out;
    unsigned long long* xbuf2 = xbuf1 + (size_t)Bv * 2 * H;

    const dim3 blk(256);

    // 1) bufA = tanh(x @ Ws + bs)
    gemm_bias_act<<<dim3(M / 64, H / 64), blk, 0, stream>>>(x, Ws, bs, nullptr, bufA, H, 1);
    // 2) bufA = linear scan -> hs_all
    scan_hs_kernel<<<dim3(H / 256, Bv / 4), blk, 0, stream>>>(bufA, tau_s);
    // 3) bufB = hs_all @ Wi + (bi + bir)
    gemm_bias_act<<<dim3(M / 64, H / 64), blk, 0, stream>>>(bufA, Wi, bi, bir, bufB, H, 0);
    // 4) bufA = hi_all  (weight-in-register recurrence, 4 blocks/row)
    recur_kernel<<<dim3(256), dim3(512), 0, stream>>>(bufB, bufA, Wir, tau_i, xbuf1);
    // 5) bufB = hi_all @ Wc + (bc + bcr)
    gemm_bias_act<<<dim3(M / 64, H / 64), blk, 0, stream>>>(bufA, Wc, bc, bcr, bufB, H, 0);
    // 6) bufA = hc_all
    recur_kernel<<<dim3(256), dim3(512), 0, stream>>>(bufB, bufA, Wcr, tau_c, xbuf2);
    // 7) out = hc_all @ Wm + bm   (overwrites the exchange region too)
    gemm_bias_act<<<dim3(M / 64, OUTD / 64), blk, 0, stream>>>(bufA, Wm, bm, nullptr, out, OUTD, 0);
}

// Round 10
// 2492.115 us; speedup vs baseline: 5.8551x; 1.0530x over previous
//
#include <hip/hip_runtime.h>
#include <cmath>

// Problem dims (fixed at compile time)
constexpr int Bv  = 64;
constexpr int T   = 512;
constexpr int H   = 512;   // h_third
constexpr int OUTD = 256;
constexpr int M   = Bv * T;  // 32768 rows for the big GEMMs

// ---------------------------------------------------------------------------
// GEMM: C[M,N] = act(A[M,512] @ W[512,N] + b1[N] (+ b2[N]))   (fp32, K=512)
// 128x128 tile, 256 threads, 8x8 microtile per thread (64 FMA : 4 LDS reads
// per k -> ~75% FMA issue duty vs 57% for the old 64x64/4x4 tile).
// ---------------------------------------------------------------------------
__global__ __launch_bounds__(256) void gemm_bias_act(
    const float* __restrict__ A, const float* __restrict__ W,
    const float* __restrict__ b1, const float* __restrict__ b2,
    float* __restrict__ C, int N, int do_tanh)
{
    constexpr int K = 512;
    __shared__ float As[16][132];   // [k][m], +4 pad: 2-way-max on transposed stores
    __shared__ float Bs[16][128];   // [k][n]

    const int tid  = threadIdx.x;
    const int row0 = blockIdx.x * 128;
    const int col0 = blockIdx.y * 128;
    const int tx = tid & 15, ty = tid >> 4;        // 16x16 thread grid

    // A staging: thread loads rows (ar, ar+64), k-chunk ak..ak+3
    const int ar = tid >> 2;            // 0..63
    const int ak = (tid & 3) * 4;       // 0,4,8,12
    // B staging: thread loads row bk, cols bn..bn+7
    const int bk = tid >> 4;            // 0..15
    const int bn = (tid & 15) * 8;

    float acc[8][8] = {};

    const float* Aptr = A + (size_t)(row0 + ar) * K + ak;
    const float* Wptr = W + (size_t)bk * N + col0 + bn;

    for (int k0 = 0; k0 < K; k0 += 16) {
        const float4 a0 = *(const float4*)(Aptr + k0);
        const float4 a1 = *(const float4*)(Aptr + (size_t)64 * K + k0);
        const float4 bv0 = *(const float4*)(Wptr + (size_t)k0 * N);
        const float4 bv1 = *(const float4*)(Wptr + (size_t)k0 * N + 4);
        As[ak + 0][ar] = a0.x;  As[ak + 1][ar] = a0.y;
        As[ak + 2][ar] = a0.z;  As[ak + 3][ar] = a0.w;
        As[ak + 0][ar + 64] = a1.x;  As[ak + 1][ar + 64] = a1.y;
        As[ak + 2][ar + 64] = a1.z;  As[ak + 3][ar + 64] = a1.w;
        *(float4*)&Bs[bk][bn]     = bv0;
        *(float4*)&Bs[bk][bn + 4] = bv1;
        __syncthreads();
        #pragma unroll
        for (int k = 0; k < 16; ++k) {
            const float4 xa = *(const float4*)&As[k][ty * 8];
            const float4 xb = *(const float4*)&As[k][ty * 8 + 4];
            const float4 ya = *(const float4*)&Bs[k][tx * 8];
            const float4 yb = *(const float4*)&Bs[k][tx * 8 + 4];
            const float a8[8] = {xa.x, xa.y, xa.z, xa.w, xb.x, xb.y, xb.z, xb.w};
            const float b8[8] = {ya.x, ya.y, ya.z, ya.w, yb.x, yb.y, yb.z, yb.w};
            #pragma unroll
            for (int i = 0; i < 8; ++i)
                #pragma unroll
                for (int j = 0; j < 8; ++j)
                    acc[i][j] = fmaf(a8[i], b8[j], acc[i][j]);
        }
        __syncthreads();
    }

    float4 bias0 = *(const float4*)&b1[col0 + tx * 8];
    float4 bias1 = *(const float4*)&b1[col0 + tx * 8 + 4];
    if (b2 != nullptr) {
        const float4 e0 = *(const float4*)&b2[col0 + tx * 8];
        const float4 e1 = *(const float4*)&b2[col0 + tx * 8 + 4];
        bias0.x += e0.x; bias0.y += e0.y; bias0.z += e0.z; bias0.w += e0.w;
        bias1.x += e1.x; bias1.y += e1.y; bias1.z += e1.z; bias1.w += e1.w;
    }
    #pragma unroll
    for (int i = 0; i < 8; ++i) {
        float4 v0, v1;
        v0.x = acc[i][0] + bias0.x;  v0.y = acc[i][1] + bias0.y;
        v0.z = acc[i][2] + bias0.z;  v0.w = acc[i][3] + bias0.w;
        v1.x = acc[i][4] + bias1.x;  v1.y = acc[i][5] + bias1.y;
        v1.z = acc[i][6] + bias1.z;  v1.w = acc[i][7] + bias1.w;
        if (do_tanh) {
            v0.x = tanhf(v0.x); v0.y = tanhf(v0.y); v0.z = tanhf(v0.z); v0.w = tanhf(v0.w);
            v1.x = tanhf(v1.x); v1.y = tanhf(v1.y); v1.z = tanhf(v1.z); v1.w = tanhf(v1.w);
        }
        float* crow = &C[(size_t)(row0 + ty * 8 + i) * N + col0 + tx * 8];
        *(float4*)crow       = v0;
        *(float4*)(crow + 4) = v1;
    }
}

// ---------------------------------------------------------------------------
// hs linear scan, in place. 2 rows/thread ILP; 64 blocks (was 32).
// ---------------------------------------------------------------------------
__global__ __launch_bounds__(256) void scan_hs_kernel(
    float* __restrict__ buf, const float* __restrict__ tau)
{
    const int h  = blockIdx.x * 256 + threadIdx.x;   // gridDim.x = 2
    const int b0 = blockIdx.y * 2;                   // gridDim.y = 32
    const float inv = 1.0f / tau[h];
    const float am  = 1.0f - inv;
    float s0 = 0.f, s1 = 0.f;
    const size_t bs_ = (size_t)T * H;
    const size_t i0 = (size_t)b0 * bs_ + h;
    #pragma unroll 4
    for (int t = 0; t < T; ++t) {
        const size_t o = i0 + (size_t)t * H;
        const float x0 = buf[o];
        const float x1 = buf[o + bs_];
        s0 = am * s0 + inv * x0;
        s1 = am * s1 + inv * x1;
        buf[o]       = s0;
        buf[o + bs_] = s1;
    }
}

// ---------------------------------------------------------------------------
// Nonlinear recurrence — UNCHANGED from round 9 (measured 847 us, correct).
// Weight-in-registers (named float4 + "+v" pins), 4 blocks/row, relaxed
// tag-in-data exchange via MALL. See round-9 notes.
// ---------------------------------------------------------------------------
#define WLOAD(i) float4 w##i = *(const float4*)&Wr[(size_t)(k0 + (i)) * H + j0];

#define PIN4(a,b,c,d) asm volatile("" :                                   \
    "+v"(a.x), "+v"(a.y), "+v"(a.z), "+v"(a.w),                           \
    "+v"(b.x), "+v"(b.y), "+v"(b.z), "+v"(b.w),                           \
    "+v"(c.x), "+v"(c.y), "+v"(c.z), "+v"(c.w),                           \
    "+v"(d.x), "+v"(d.y), "+v"(d.z), "+v"(d.w));

#define FMAG(wa, wb, wc, wd)                              \
    acc.x = fmaf(h4.x, wa.x, acc.x);                      \
    acc.y = fmaf(h4.x, wa.y, acc.y);                      \
    acc.z = fmaf(h4.x, wa.z, acc.z);                      \
    acc.w = fmaf(h4.x, wa.w, acc.w);                      \
    acc.x = fmaf(h4.y, wb.x, acc.x);                      \
    acc.y = fmaf(h4.y, wb.y, acc.y);                      \
    acc.z = fmaf(h4.y, wb.z, acc.z);                      \
    acc.w = fmaf(h4.y, wb.w, acc.w);                      \
    acc.x = fmaf(h4.z, wc.x, acc.x);                      \
    acc.y = fmaf(h4.z, wc.y, acc.y);                      \
    acc.z = fmaf(h4.z, wc.z, acc.z);                      \
    acc.w = fmaf(h4.z, wc.w, acc.w);                      \
    acc.x = fmaf(h4.w, wd.x, acc.x);                      \
    acc.y = fmaf(h4.w, wd.y, acc.y);                      \
    acc.z = fmaf(h4.w, wd.z, acc.z);                      \
    acc.w = fmaf(h4.w, wd.w, acc.w);

__global__ __launch_bounds__(512)
__attribute__((amdgpu_waves_per_eu(2, 2)))
void recur_kernel(
    const float* __restrict__ U, float* __restrict__ Hout,
    const float* __restrict__ Wr, const float* __restrict__ tau,
    unsigned long long* __restrict__ xbuf)
{
    __shared__ float h_lds[H];          // full previous state h_{t-1}
    __shared__ float accb[16][128];     // partials: [k-slice][local col]

    const int tid = threadIdx.x;
    const int bid = blockIdx.x;
    const int x = bid & 7, q = bid >> 3;
    const int r = (q >> 2) * 8 + x;     // batch row 0..63
    const int p = q & 3;                // column quarter 0..3
    const int p128 = p * 128;

    const int cg = tid & 31;            // col group: cols 4cg..4cg+3 (local)
    const int s  = tid >> 5;            // k-slice: [32s, 32s+32)
    const int k0 = s * 32;
    const int j0 = p128 + cg * 4;       // global col of this thread's 4 cols

    WLOAD(0)  WLOAD(1)  WLOAD(2)  WLOAD(3)
    WLOAD(4)  WLOAD(5)  WLOAD(6)  WLOAD(7)
    WLOAD(8)  WLOAD(9)  WLOAD(10) WLOAD(11)
    WLOAD(12) WLOAD(13) WLOAD(14) WLOAD(15)
    WLOAD(16) WLOAD(17) WLOAD(18) WLOAD(19)
    WLOAD(20) WLOAD(21) WLOAD(22) WLOAD(23)
    WLOAD(24) WLOAD(25) WLOAD(26) WLOAD(27)
    WLOAD(28) WLOAD(29) WLOAD(30) WLOAD(31)

    float inv = 0.f, am = 0.f, h_reg = 0.f;
    const float* Urow = nullptr;
    float*       Hrow = nullptr;
    if (tid < 128) {
        inv = 1.0f / tau[p128 + tid];
        am  = 1.0f - inv;
        Urow = U    + (size_t)r * T * H + p128 + tid;
        Hrow = Hout + (size_t)r * T * H + p128 + tid;
    }
    unsigned long long* __restrict__ xrow = xbuf + (size_t)r * 2 * H;

    h_lds[tid] = 0.0f;
    __syncthreads();

    float uval = 0.f, unext = 0.f;
    if (tid < 128) uval = Urow[0];

    for (int t = 0; t < T; ++t) {
        PIN4(w0,  w1,  w2,  w3)   PIN4(w4,  w5,  w6,  w7)
        PIN4(w8,  w9,  w10, w11)  PIN4(w12, w13, w14, w15)
        PIN4(w16, w17, w18, w19)  PIN4(w20, w21, w22, w23)
        PIN4(w24, w25, w26, w27)  PIN4(w28, w29, w30, w31)

        if (tid < 128 && t + 1 < T) unext = Urow[(size_t)(t + 1) * H];

        float4 acc = make_float4(0.f, 0.f, 0.f, 0.f);
        float4 h4;
        h4 = *(const float4*)&h_lds[k0 +  0]; FMAG(w0,  w1,  w2,  w3)
        h4 = *(const float4*)&h_lds[k0 +  4]; FMAG(w4,  w5,  w6,  w7)
        h4 = *(const float4*)&h_lds[k0 +  8]; FMAG(w8,  w9,  w10, w11)
        h4 = *(const float4*)&h_lds[k0 + 12]; FMAG(w12, w13, w14, w15)
        h4 = *(const float4*)&h_lds[k0 + 16]; FMAG(w16, w17, w18, w19)
        h4 = *(const float4*)&h_lds[k0 + 20]; FMAG(w20, w21, w22, w23)
        h4 = *(const float4*)&h_lds[k0 + 24]; FMAG(w24, w25, w26, w27)
        h4 = *(const float4*)&h_lds[k0 + 28]; FMAG(w28, w29, w30, w31)
        *(float4*)&accb[s][cg * 4] = acc;
        __syncthreads();

        if (tid < 128) {
            float red = 0.f;
            #pragma unroll
            for (int ss = 0; ss < 16; ++ss) red += accb[ss][tid];
            const float a = red + uval;
            const float hnew = am * h_reg + inv * tanhf(a);
            h_reg = hnew;
            if (t + 1 < T) {
                const unsigned long long pv =
                    ((unsigned long long)(unsigned)(t + 1) << 32) |
                    (unsigned long long)__float_as_uint(hnew);
                __hip_atomic_store(&xrow[(size_t)(t & 1) * H + p128 + tid], pv,
                                   __ATOMIC_RELAXED, __HIP_MEMORY_SCOPE_AGENT);
            }
            Hrow[(size_t)t * H] = hnew;
            h_lds[p128 + tid] = hnew;
        }

        if (t + 1 < T) {
            if (tid >= 128) {
                const int e = (p128 + tid) & 511;
                unsigned long long* slot = &xrow[(size_t)(t & 1) * H + e];
                unsigned long long v;
                do {
                    v = __hip_atomic_load(slot, __ATOMIC_RELAXED,
                                          __HIP_MEMORY_SCOPE_AGENT);
                } while ((int)(v >> 32) != t + 1);
                h_lds[e] = __uint_as_float((unsigned)v);
            }
            uval = unext;
            __syncthreads();
        }
    }
}

// ---------------------------------------------------------------------------
extern "C" void kernel_launch(void* const* d_in, const int* in_sizes, int n_in,
                              void* d_out, int out_size, void* d_ws, size_t ws_size,
                              hipStream_t stream)
{
    const float* x     = (const float*)d_in[0];
    const float* Ws    = (const float*)d_in[1];
    const float* bs    = (const float*)d_in[2];
    const float* Wi    = (const float*)d_in[3];
    const float* bi    = (const float*)d_in[4];
    const float* Wc    = (const float*)d_in[5];
    const float* bc    = (const float*)d_in[6];
    const float* Wm    = (const float*)d_in[7];
    const float* bm    = (const float*)d_in[8];
    const float* Wir   = (const float*)d_in[9];
    const float* bir   = (const float*)d_in[10];
    const float* Wcr   = (const float*)d_in[11];
    const float* bcr   = (const float*)d_in[12];
    const float* tau_s = (const float*)d_in[13];
    const float* tau_i = (const float*)d_in[14];
    const float* tau_c = (const float*)d_in[15];
    float* out = (float*)d_out;

    float* bufA = (float*)d_ws;                 // [B,T,H]  64 MB
    float* bufB = bufA + (size_t)M * H;         // [B,T,H]  64 MB
    // Exchange buffers at the start of d_out (0xAA poison -> negative tags;
    // overwritten by the final GEMM). Each: 64 x 2 x 512 x 8B = 512 KB.
    unsigned long long* xbuf1 = (unsigned long long*)d_out;
    unsigned long long* xbuf2 = xbuf1 + (size_t)Bv * 2 * H;

    const dim3 blk(256);

    // 1) bufA = tanh(x @ Ws + bs)
    gemm_bias_act<<<dim3(M / 128, H / 128), blk, 0, stream>>>(x, Ws, bs, nullptr, bufA, H, 1);
    // 2) bufA = linear scan -> hs_all
    scan_hs_kernel<<<dim3(H / 256, Bv / 2), blk, 0, stream>>>(bufA, tau_s);
    // 3) bufB = hs_all @ Wi + (bi + bir)
    gemm_bias_act<<<dim3(M / 128, H / 128), blk, 0, stream>>>(bufA, Wi, bi, bir, bufB, H, 0);
    // 4) bufA = hi_all  (weight-in-register recurrence, 4 blocks/row)
    recur_kernel<<<dim3(256), dim3(512), 0, stream>>>(bufB, bufA, Wir, tau_i, xbuf1);
    // 5) bufB = hi_all @ Wc + (bc + bcr)
    gemm_bias_act<<<dim3(M / 128, H / 128), blk, 0, stream>>>(bufA, Wc, bc, bcr, bufB, H, 0);
    // 6) bufA = hc_all
    recur_kernel<<<dim3(256), dim3(512), 0, stream>>>(bufB, bufA, Wcr, tau_c, xbuf2);
    // 7) out = hc_all @ Wm + bm   (overwrites the exchange region too)
    gemm_bias_act<<<dim3(M / 128, OUTD / 128), blk, 0, stream>>>(bufA, Wm, bm, nullptr, out, OUTD, 0);
}

// Round 11
// 2104.087 us; speedup vs baseline: 6.9348x; 1.1844x over previous
//
#include <hip/hip_runtime.h>
#include <cmath>

// Problem dims (fixed at compile time)
constexpr int Bv  = 64;
constexpr int T   = 512;
constexpr int H   = 512;   // h_third
constexpr int OUTD = 256;
constexpr int M   = Bv * T;  // 32768 rows for the big GEMMs

typedef __attribute__((ext_vector_type(8))) short short8;
typedef __attribute__((ext_vector_type(4))) short short4v;
typedef __attribute__((ext_vector_type(4))) float f32x4;

// round-to-nearest fp32 -> bf16 bits
__device__ __forceinline__ unsigned short bf16_rn(float f) {
    unsigned u = __float_as_uint(f);
    return (unsigned short)((u + 0x7FFFu + ((u >> 16) & 1u)) >> 16);
}
// split f = hi + lo + O(2^-17 f)
__device__ __forceinline__ void split2(float f, unsigned short& h, unsigned short& l) {
    h = bf16_rn(f);
    l = bf16_rn(f - __uint_as_float(((unsigned)h) << 16));
}

// ---------------------------------------------------------------------------
// MFMA GEMM: C[M,N] = act(A[M,512] @ W[512,N] + b1 (+ b2)), fp32 in/out.
// Split-precision bf16x2 (4 cross-terms) on mfma_f32_16x16x32_bf16.
// 128x128 tile, 256 thr = 4 waves (2x2), 64x64 per wave = 4x4 16x16 frags.
// Verified layouts (learn_hip m89/m91/m92): A frag lane l <- A[m=l&15][k=(l>>4)*8+e]
// (8 contiguous k); B frag lane l <- W[k=(l>>4)*8+e][n=l&15] read from
// transposed LDS Wt[n][k]; C/D: col=lane&15, row=(lane>>4)*4+reg.
// ---------------------------------------------------------------------------
__global__ __launch_bounds__(256) void gemm_mfma(
    const float* __restrict__ A, const float* __restrict__ W,
    const float* __restrict__ b1, const float* __restrict__ b2,
    float* __restrict__ C, int N, int do_tanh)
{
    constexpr int K = 512;
    constexpr int P = 40;   // padded k-stride in shorts (80B, 16B-aligned rows)
    __shared__ unsigned short Ah[128][P], Al[128][P];   // A tile [m][k]
    __shared__ unsigned short Wh[128][P], Wl[128][P];   // W^T tile [n][k], XOR-swizzled

    const int tid  = threadIdx.x;
    const int lane = tid & 63;
    const int wid  = tid >> 6;             // 0..3
    const int wm   = wid >> 1, wn = wid & 1;
    const int row0 = blockIdx.x * 128;
    const int col0 = blockIdx.y * 128;

    const int l15 = lane & 15;
    const int l4  = lane >> 4;
    const int kb  = l4 * 8;                // fragment k-base

    // A staging: thread -> row am, k-half akq (16 floats)
    const int am  = tid >> 1;
    const int akq = (tid & 1) * 16;
    // W staging: thread -> 4k x 4n block
    const int wk4 = (tid >> 5) * 4;        // 0..28
    const int wn4 = (tid & 31) * 4;        // 0..124

    f32x4 acc[4][4];
    #pragma unroll
    for (int i = 0; i < 4; ++i)
        #pragma unroll
        for (int j = 0; j < 4; ++j) {
            f32x4 z = {0.f, 0.f, 0.f, 0.f};
            acc[i][j] = z;
        }

    for (int k0 = 0; k0 < K; k0 += 32) {
        // ---- stage A (128 x 32 fp32 -> hi/lo bf16) ----
        {
            const float* ap = A + (size_t)(row0 + am) * K + k0 + akq;
            #pragma unroll
            for (int c = 0; c < 4; ++c) {
                const float4 v = *(const float4*)(ap + c * 4);
                unsigned short h0, l0, h1, l1, h2, l2, h3, l3;
                split2(v.x, h0, l0); split2(v.y, h1, l1);
                split2(v.z, h2, l2); split2(v.w, h3, l3);
                short4v sh = {(short)h0, (short)h1, (short)h2, (short)h3};
                short4v sl = {(short)l0, (short)l1, (short)l2, (short)l3};
                *(short4v*)&Ah[am][akq + c * 4] = sh;
                *(short4v*)&Al[am][akq + c * 4] = sl;
            }
        }
        // ---- stage W transposed (32 x 128 fp32 -> Wt[n][k] hi/lo, swizzled) ----
        {
            float arr[4][4];
            #pragma unroll
            for (int i = 0; i < 4; ++i) {
                const float4 v = *(const float4*)(W + (size_t)(k0 + wk4 + i) * N + col0 + wn4);
                arr[i][0] = v.x; arr[i][1] = v.y; arr[i][2] = v.z; arr[i][3] = v.w;
            }
            #pragma unroll
            for (int j = 0; j < 4; ++j) {
                const int n = wn4 + j;
                const int kbase = wk4 ^ (((n >> 2) & 3) << 3);   // 8-granular XOR swizzle
                unsigned short h0, l0, h1, l1, h2, l2, h3, l3;
                split2(arr[0][j], h0, l0); split2(arr[1][j], h1, l1);
                split2(arr[2][j], h2, l2); split2(arr[3][j], h3, l3);
                short4v sh = {(short)h0, (short)h1, (short)h2, (short)h3};
                short4v sl = {(short)l0, (short)l1, (short)l2, (short)l3};
                *(short4v*)&Wh[n][kbase] = sh;
                *(short4v*)&Wl[n][kbase] = sl;
            }
        }
        __syncthreads();

        // ---- compute: 4x4 fragments, 4 cross-terms each ----
        short8 ahf[4], alf[4];
        #pragma unroll
        for (int fi = 0; fi < 4; ++fi) {
            const int r = wm * 64 + fi * 16 + l15;
            ahf[fi] = *(const short8*)&Ah[r][kb];
            alf[fi] = *(const short8*)&Al[r][kb];
        }
        #pragma unroll
        for (int fj = 0; fj < 4; ++fj) {
            const int n  = wn * 64 + fj * 16 + l15;
            const int kk = kb ^ (((n >> 2) & 3) << 3);
            const short8 bh = *(const short8*)&Wh[n][kk];
            const short8 bl = *(const short8*)&Wl[n][kk];
            #pragma unroll
            for (int fi = 0; fi < 4; ++fi) {
                acc[fi][fj] = __builtin_amdgcn_mfma_f32_16x16x32_bf16(ahf[fi], bh, acc[fi][fj], 0, 0, 0);
                acc[fi][fj] = __builtin_amdgcn_mfma_f32_16x16x32_bf16(alf[fi], bh, acc[fi][fj], 0, 0, 0);
                acc[fi][fj] = __builtin_amdgcn_mfma_f32_16x16x32_bf16(ahf[fi], bl, acc[fi][fj], 0, 0, 0);
                acc[fi][fj] = __builtin_amdgcn_mfma_f32_16x16x32_bf16(alf[fi], bl, acc[fi][fj], 0, 0, 0);
            }
        }
        __syncthreads();
    }

    // ---- epilogue: bias (+b2), optional tanh, scalar fp32 stores ----
    #pragma unroll
    for (int fj = 0; fj < 4; ++fj) {
        const int col = col0 + wn * 64 + fj * 16 + l15;
        float bias = b1[col];
        if (b2 != nullptr) bias += b2[col];
        #pragma unroll
        for (int fi = 0; fi < 4; ++fi) {
            const int rbase = row0 + wm * 64 + fi * 16 + l4 * 4;
            #pragma unroll
            for (int j = 0; j < 4; ++j) {
                float v = acc[fi][fj][j] + bias;
                if (do_tanh) v = tanhf(v);
                C[(size_t)(rbase + j) * N + col] = v;
            }
        }
    }
}

// ---------------------------------------------------------------------------
// hs linear scan, in place (unchanged from round 10)
// ---------------------------------------------------------------------------
__global__ __launch_bounds__(256) void scan_hs_kernel(
    float* __restrict__ buf, const float* __restrict__ tau)
{
    const int h  = blockIdx.x * 256 + threadIdx.x;   // gridDim.x = 2
    const int b0 = blockIdx.y * 2;                   // gridDim.y = 32
    const float inv = 1.0f / tau[h];
    const float am  = 1.0f - inv;
    float s0 = 0.f, s1 = 0.f;
    const size_t bs_ = (size_t)T * H;
    const size_t i0 = (size_t)b0 * bs_ + h;
    #pragma unroll 4
    for (int t = 0; t < T; ++t) {
        const size_t o = i0 + (size_t)t * H;
        const float x0 = buf[o];
        const float x1 = buf[o + bs_];
        s0 = am * s0 + inv * x0;
        s1 = am * s1 + inv * x1;
        buf[o]       = s0;
        buf[o + bs_] = s1;
    }
}

// ---------------------------------------------------------------------------
// Nonlinear recurrence — UNCHANGED (measured 847-852 us, latency-floor).
// Weight-in-registers (named float4 + "+v" pins), 4 blocks/row, relaxed
// tag-in-data exchange via MALL.
// ---------------------------------------------------------------------------
#define WLOAD(i) float4 w##i = *(const float4*)&Wr[(size_t)(k0 + (i)) * H + j0];

#define PIN4(a,b,c,d) asm volatile("" :                                   \
    "+v"(a.x), "+v"(a.y), "+v"(a.z), "+v"(a.w),                           \
    "+v"(b.x), "+v"(b.y), "+v"(b.z), "+v"(b.w),                           \
    "+v"(c.x), "+v"(c.y), "+v"(c.z), "+v"(c.w),                           \
    "+v"(d.x), "+v"(d.y), "+v"(d.z), "+v"(d.w));

#define FMAG(wa, wb, wc, wd)                              \
    acc.x = fmaf(h4.x, wa.x, acc.x);                      \
    acc.y = fmaf(h4.x, wa.y, acc.y);                      \
    acc.z = fmaf(h4.x, wa.z, acc.z);                      \
    acc.w = fmaf(h4.x, wa.w, acc.w);                      \
    acc.x = fmaf(h4.y, wb.x, acc.x);                      \
    acc.y = fmaf(h4.y, wb.y, acc.y);                      \
    acc.z = fmaf(h4.y, wb.z, acc.z);                      \
    acc.w = fmaf(h4.y, wb.w, acc.w);                      \
    acc.x = fmaf(h4.z, wc.x, acc.x);                      \
    acc.y = fmaf(h4.z, wc.y, acc.y);                      \
    acc.z = fmaf(h4.z, wc.z, acc.z);                      \
    acc.w = fmaf(h4.z, wc.w, acc.w);                      \
    acc.x = fmaf(h4.w, wd.x, acc.x);                      \
    acc.y = fmaf(h4.w, wd.y, acc.y);                      \
    acc.z = fmaf(h4.w, wd.z, acc.z);                      \
    acc.w = fmaf(h4.w, wd.w, acc.w);

__global__ __launch_bounds__(512)
__attribute__((amdgpu_waves_per_eu(2, 2)))
void recur_kernel(
    const float* __restrict__ U, float* __restrict__ Hout,
    const float* __restrict__ Wr, const float* __restrict__ tau,
    unsigned long long* __restrict__ xbuf)
{
    __shared__ float h_lds[H];          // full previous state h_{t-1}
    __shared__ float accb[16][128];     // partials: [k-slice][local col]

    const int tid = threadIdx.x;
    const int bid = blockIdx.x;
    const int x = bid & 7, q = bid >> 3;
    const int r = (q >> 2) * 8 + x;     // batch row 0..63
    const int p = q & 3;                // column quarter 0..3
    const int p128 = p * 128;

    const int cg = tid & 31;            // col group: cols 4cg..4cg+3 (local)
    const int s  = tid >> 5;            // k-slice: [32s, 32s+32)
    const int k0 = s * 32;
    const int j0 = p128 + cg * 4;       // global col of this thread's 4 cols

    WLOAD(0)  WLOAD(1)  WLOAD(2)  WLOAD(3)
    WLOAD(4)  WLOAD(5)  WLOAD(6)  WLOAD(7)
    WLOAD(8)  WLOAD(9)  WLOAD(10) WLOAD(11)
    WLOAD(12) WLOAD(13) WLOAD(14) WLOAD(15)
    WLOAD(16) WLOAD(17) WLOAD(18) WLOAD(19)
    WLOAD(20) WLOAD(21) WLOAD(22) WLOAD(23)
    WLOAD(24) WLOAD(25) WLOAD(26) WLOAD(27)
    WLOAD(28) WLOAD(29) WLOAD(30) WLOAD(31)

    float inv = 0.f, am = 0.f, h_reg = 0.f;
    const float* Urow = nullptr;
    float*       Hrow = nullptr;
    if (tid < 128) {
        inv = 1.0f / tau[p128 + tid];
        am  = 1.0f - inv;
        Urow = U    + (size_t)r * T * H + p128 + tid;
        Hrow = Hout + (size_t)r * T * H + p128 + tid;
    }
    unsigned long long* __restrict__ xrow = xbuf + (size_t)r * 2 * H;

    h_lds[tid] = 0.0f;
    __syncthreads();

    float uval = 0.f, unext = 0.f;
    if (tid < 128) uval = Urow[0];

    for (int t = 0; t < T; ++t) {
        PIN4(w0,  w1,  w2,  w3)   PIN4(w4,  w5,  w6,  w7)
        PIN4(w8,  w9,  w10, w11)  PIN4(w12, w13, w14, w15)
        PIN4(w16, w17, w18, w19)  PIN4(w20, w21, w22, w23)
        PIN4(w24, w25, w26, w27)  PIN4(w28, w29, w30, w31)

        if (tid < 128 && t + 1 < T) unext = Urow[(size_t)(t + 1) * H];

        float4 acc = make_float4(0.f, 0.f, 0.f, 0.f);
        float4 h4;
        h4 = *(const float4*)&h_lds[k0 +  0]; FMAG(w0,  w1,  w2,  w3)
        h4 = *(const float4*)&h_lds[k0 +  4]; FMAG(w4,  w5,  w6,  w7)
        h4 = *(const float4*)&h_lds[k0 +  8]; FMAG(w8,  w9,  w10, w11)
        h4 = *(const float4*)&h_lds[k0 + 12]; FMAG(w12, w13, w14, w15)
        h4 = *(const float4*)&h_lds[k0 + 16]; FMAG(w16, w17, w18, w19)
        h4 = *(const float4*)&h_lds[k0 + 20]; FMAG(w20, w21, w22, w23)
        h4 = *(const float4*)&h_lds[k0 + 24]; FMAG(w24, w25, w26, w27)
        h4 = *(const float4*)&h_lds[k0 + 28]; FMAG(w28, w29, w30, w31)
        *(float4*)&accb[s][cg * 4] = acc;
        __syncthreads();

        if (tid < 128) {
            float red = 0.f;
            #pragma unroll
            for (int ss = 0; ss < 16; ++ss) red += accb[ss][tid];
            const float a = red + uval;
            const float hnew = am * h_reg + inv * tanhf(a);
            h_reg = hnew;
            if (t + 1 < T) {
                const unsigned long long pv =
                    ((unsigned long long)(unsigned)(t + 1) << 32) |
                    (unsigned long long)__float_as_uint(hnew);
                __hip_atomic_store(&xrow[(size_t)(t & 1) * H + p128 + tid], pv,
                                   __ATOMIC_RELAXED, __HIP_MEMORY_SCOPE_AGENT);
            }
            Hrow[(size_t)t * H] = hnew;
            h_lds[p128 + tid] = hnew;
        }

        if (t + 1 < T) {
            if (tid >= 128) {
                const int e = (p128 + tid) & 511;
                unsigned long long* slot = &xrow[(size_t)(t & 1) * H + e];
                unsigned long long v;
                do {
                    v = __hip_atomic_load(slot, __ATOMIC_RELAXED,
                                          __HIP_MEMORY_SCOPE_AGENT);
                } while ((int)(v >> 32) != t + 1);
                h_lds[e] = __uint_as_float((unsigned)v);
            }
            uval = unext;
            __syncthreads();
        }
    }
}

// ---------------------------------------------------------------------------
extern "C" void kernel_launch(void* const* d_in, const int* in_sizes, int n_in,
                              void* d_out, int out_size, void* d_ws, size_t ws_size,
                              hipStream_t stream)
{
    const float* x     = (const float*)d_in[0];
    const float* Ws    = (const float*)d_in[1];
    const float* bs    = (const float*)d_in[2];
    const float* Wi    = (const float*)d_in[3];
    const float* bi    = (const float*)d_in[4];
    const float* Wc    = (const float*)d_in[5];
    const float* bc    = (const float*)d_in[6];
    const float* Wm    = (const float*)d_in[7];
    const float* bm    = (const float*)d_in[8];
    const float* Wir   = (const float*)d_in[9];
    const float* bir   = (const float*)d_in[10];
    const float* Wcr   = (const float*)d_in[11];
    const float* bcr   = (const float*)d_in[12];
    const float* tau_s = (const float*)d_in[13];
    const float* tau_i = (const float*)d_in[14];
    const float* tau_c = (const float*)d_in[15];
    float* out = (float*)d_out;

    float* bufA = (float*)d_ws;                 // [B,T,H]  64 MB
    float* bufB = bufA + (size_t)M * H;         // [B,T,H]  64 MB
    // Exchange buffers at the start of d_out (0xAA poison -> negative tags;
    // overwritten by the final GEMM). Each: 64 x 2 x 512 x 8B = 512 KB.
    unsigned long long* xbuf1 = (unsigned long long*)d_out;
    unsigned long long* xbuf2 = xbuf1 + (size_t)Bv * 2 * H;

    const dim3 blk(256);

    // 1) bufA = tanh(x @ Ws + bs)
    gemm_mfma<<<dim3(M / 128, H / 128), blk, 0, stream>>>(x, Ws, bs, nullptr, bufA, H, 1);
    // 2) bufA = linear scan -> hs_all
    scan_hs_kernel<<<dim3(H / 256, Bv / 2), blk, 0, stream>>>(bufA, tau_s);
    // 3) bufB = hs_all @ Wi + (bi + bir)
    gemm_mfma<<<dim3(M / 128, H / 128), blk, 0, stream>>>(bufA, Wi, bi, bir, bufB, H, 0);
    // 4) bufA = hi_all  (weight-in-register recurrence, 4 blocks/row)
    recur_kernel<<<dim3(256), dim3(512), 0, stream>>>(bufB, bufA, Wir, tau_i, xbuf1);
    // 5) bufB = hi_all @ Wc + (bc + bcr)
    gemm_mfma<<<dim3(M / 128, H / 128), blk, 0, stream>>>(bufA, Wc, bc, bcr, bufB, H, 0);
    // 6) bufA = hc_all
    recur_kernel<<<dim3(256), dim3(512), 0, stream>>>(bufB, bufA, Wcr, tau_c, xbuf2);
    // 7) out = hc_all @ Wm + bm   (overwrites the exchange region too)
    gemm_mfma<<<dim3(M / 128, OUTD / 128), blk, 0, stream>>>(bufA, Wm, bm, nullptr, out, OUTD, 0);
}